// Round 14
// baseline (190.246 us; speedup 1.0000x reference)
//
#include <hip/hip_runtime.h>
#include <math.h>

// Problem constants (B=16, C=3, H=W=512) -> 48 "rows" (images) of L = 262144 elements.
constexpr int W = 512;
constexpr int HIMG = 512;
constexpr int L = 1 << 18;                // elements per row
constexpr int LOG2L = 18;
constexpr int TPB = 256;
constexpr int TPB1 = 1024;                // K1 block size (R14: 512->1024, 4th use of the lever)
constexpr int TPB4 = 512;                 // K4 block size (R13-proven)
constexpr int TILE = 2048;                // elements per scatter tile (= 4 scanlines)
constexpr int TILES_PER_ROW = L / TILE;   // 128
constexpr int WORDS_PER_TILE = TILE / 64; // 32
constexpr int SPB = 16;                   // scanlines per fused-mask block (R8-proven)
constexpr int HALO = 3;
constexpr int HBUF = SPB + 2 * HALO;      // 22
constexpr int BLK_PER_IMG = HIMG / SPB;   // 32
constexpr int LBLK = 32;                  // loss blocks per row (1536 blocks, unchanged)
constexpr int LOG2LBLK = 5;
constexpr int CHUNK = L / LBLK;           // 8192 elements per loss block
constexpr int LIT = CHUNK / (TPB4 * 4);   // 4 float4 iterations per thread

typedef unsigned long long ull;

// softplus via native v_exp_f32 / v_log_f32 (abs err ~1e-6; threshold 3.6e-2)
__device__ __forceinline__ float softplus_f(float v) {
    return fmaxf(v, 0.0f) +
           0.6931471805599453f *
               __builtin_amdgcn_logf(1.0f + __builtin_amdgcn_exp2f(-fabsf(v) * 1.4426950408889634f));
}

__device__ __forceinline__ ull hdil7(ull prev, ull cur, ull next) {
    ull r = cur;
    r |= (cur >> 1) | (next << 63);
    r |= (cur >> 2) | (next << 62);
    r |= (cur >> 3) | (next << 61);
    r |= (cur << 1) | (prev >> 63);
    r |= (cur << 2) | (prev >> 62);
    r |= (cur << 3) | (prev >> 61);
    return r;
}

template <typename T>
__device__ __forceinline__ T sel8(const T* a, int k) {
    return k == 0 ? a[0] : k == 1 ? a[1] : k == 2 ? a[2] : k == 3 ? a[3]
         : k == 4 ? a[4] : k == 5 ? a[5] : k == 6 ? a[6] : a[7];
}

// ------ K1: fused masks + 7x7 dilation + per-tile counts. One block = 16 scanlines. ------
// R14: TPB 512->1024 at the same 1536-block grid. Waves/CU unchanged (2 blocks x 16
// waves = 32 = cap) but per-wave serial scanline chain drops 2.75 -> 1.4 iterations
// at constant total instruction count (the R10/R13 mechanism). Also zeroes K4's
// done-counter (kernel-boundary ordering makes it visible to K4).
__global__ __launch_bounds__(TPB1)
void fused_mask_kernel(const float* __restrict__ x, const float* __restrict__ t,
                       ull* __restrict__ mT, ull* __restrict__ mFp, ull* __restrict__ mNeg,
                       int* __restrict__ cPos, int* __restrict__ cFp, int* __restrict__ cNeg,
                       unsigned int* __restrict__ doneCnt) {
    if (blockIdx.x == 0 && threadIdx.x == 0) *doneCnt = 0u;  // ws is poisoned each iter
    int b = blockIdx.x;
    int img = b >> 5;              // BLK_PER_IMG = 32
    int y0 = (b & 31) * SPB;       // image-local scanline base
    int gs0 = img * HIMG + y0;     // global scanline index of own base

    __shared__ ull hbuf[HBUF][8];  // h-dilated words incl. halo
    __shared__ ull tbuf[SPB][8];
    __shared__ ull xbuf[SPB][8];

    int lane = threadIdx.x & 63;
    int wv = threadIdx.x >> 6;     // wave 0..15
    int ylo = (y0 - HALO < 0) ? 0 : y0 - HALO;
    int yhi = (y0 + SPB - 1 + HALO > HIMG - 1) ? HIMG - 1 : y0 + SPB - 1 + HALO;

    for (int yl = ylo + wv; yl <= yhi; yl += 16) {
        int gbase = (img * HIMG + yl) * W;
        bool own = (yl >= y0) && (yl < y0 + SPB);
        ull wt[8], wx[8], h[8];
#pragma unroll
        for (int k = 0; k < 8; ++k) wt[k] = __ballot(t[gbase + k * 64 + lane] > 0.0f);
        if (own) {
#pragma unroll
            for (int k = 0; k < 8; ++k) wx[k] = __ballot(x[gbase + k * 64 + lane] > 0.0f);
        }
#pragma unroll
        for (int k = 0; k < 8; ++k) {
            ull cur = wt[k];
            ull prev = k ? wt[k - 1]
                         : ((((cur >> 1) & 1ull) << 63) | (((cur >> 2) & 1ull) << 62) |
                            (((cur >> 3) & 1ull) << 61));
            ull next = (k < 7) ? wt[k + 1]
                               : (((cur >> 62) & 1ull) | (((cur >> 61) & 1ull) << 1) |
                                  (((cur >> 60) & 1ull) << 2));
            h[k] = hdil7(prev, cur, next);
        }
        int hy = yl - (y0 - HALO);
        int k = lane & 7;
        if (lane < 8) {
            hbuf[hy][k] = sel8(h, k);
        } else if (own && lane < 16) {
            tbuf[yl - y0][k] = sel8(wt, k);
            mT[(img * HIMG + yl) * 8 + k] = sel8(wt, k);
        } else if (own && lane < 24) {
            xbuf[yl - y0][k] = sel8(wx, k);
        }
    }
    __syncthreads();

    // phase 2: vertical dilation + per-word popcounts; thread = one own word
    int tid = threadIdx.x;
    if (tid < SPB * 8) {           // 128 active threads (16 scanlines x 8 words)
        int ys = tid >> 3;         // own scanline offset 0..15
        int c = tid & 7;
        int y = y0 + ys;
        ull wa = 0;
#pragma unroll
        for (int d = -3; d <= 3; ++d) {
            int yy = y + d;
            yy = yy < 0 ? -yy : (yy > HIMG - 1 ? 2 * (HIMG - 1) - yy : yy);
            wa |= hbuf[yy - (y0 - HALO)][c];
        }
        ull tw = tbuf[ys][c];
        ull fp = xbuf[ys][c] & ~wa;
        ull ng = ~wa;
        int gw = gs0 * 8 + tid;
        mFp[gw] = fp;
        mNeg[gw] = ng;
        int pT = __popcll(tw), pF = __popcll(fp), pN = __popcll(ng);
        // reduce within 32-thread groups (one tile = 4 scanlines = 32 words)
#pragma unroll
        for (int m = 1; m < 32; m <<= 1) {
            pT += __shfl_xor(pT, m, 64);
            pF += __shfl_xor(pF, m, 64);
            pN += __shfl_xor(pN, m, 64);
        }
        if ((lane & 31) == 0) {
            int tile = img * TILES_PER_ROW + (y0 >> 2) + (tid >> 5);
            cPos[tile] = pT; cFp[tile] = pF; cNeg[tile] = pN;
        }
    }
}

// ------ K2: per-row scan of tile counts + magic divisors (R10 version) ------
__global__ void scan_kernel(const int* __restrict__ cPos, const int* __restrict__ cFp,
                            const int* __restrict__ cNeg,
                            int* __restrict__ oPos, int* __restrict__ oCh,
                            int* __restrict__ rCp, int* __restrict__ rCc,
                            ull* __restrict__ rMp, ull* __restrict__ rMc,
                            int* __restrict__ rUseFp) {
    int r = blockIdx.x;
    int tid = threadIdx.x;  // blockDim == TILES_PER_ROW
    __shared__ int ssp[TILES_PER_ROW], ssf[TILES_PER_ROW], ssn[TILES_PER_ROW];
    int myp = cPos[r * TILES_PER_ROW + tid];
    int myf = cFp[r * TILES_PER_ROW + tid];
    int myn = cNeg[r * TILES_PER_ROW + tid];
    ssp[tid] = myp; ssf[tid] = myf; ssn[tid] = myn;
    __syncthreads();
    for (int off = 1; off < TILES_PER_ROW; off <<= 1) {
        int ap = 0, af = 0, an = 0;
        if (tid >= off) { ap = ssp[tid - off]; af = ssf[tid - off]; an = ssn[tid - off]; }
        __syncthreads();
        if (tid >= off) { ssp[tid] += ap; ssf[tid] += af; ssn[tid] += an; }
        __syncthreads();
    }
    int cp = ssp[TILES_PER_ROW - 1], cf = ssf[TILES_PER_ROW - 1], cn = ssn[TILES_PER_ROW - 1];
    bool useFp = cf > 0;
    int tile = r * TILES_PER_ROW + tid;
    oPos[tile] = ssp[tid] - myp;
    oCh[tile] = useFp ? (ssf[tid] - myf) : (ssn[tid] - myn);
    if (tid == 0) {
        int cc = useFp ? cf : cn;
        rCp[r] = cp; rCc[r] = cc; rUseFp[r] = useFp ? 1 : 0;
        ull dp_ = (ull)(cp > 0 ? cp : 1);
        ull dc_ = (ull)(cc > 0 ? cc : 1);
        rMp[r] = ((1ull << 40) + dp_ - 1) / dp_;  // exact floor(n/d) for n < 2^22
        rMc[r] = ((1ull << 40) + dc_ - 1) / dc_;
    }
}

// ------ K3: scatter-compaction (R12 version: shfl-scan + aligned-vectorized stores) ------
__global__ __launch_bounds__(TPB)
void scatter_kernel(const float* __restrict__ x, const ull* __restrict__ mT,
                    const ull* __restrict__ mFp, const ull* __restrict__ mNeg,
                    const int* __restrict__ oPos, const int* __restrict__ oCh,
                    const int* __restrict__ rUseFp,
                    float* __restrict__ xp, float* __restrict__ xf) {
    int tile = blockIdx.x;
    int tid = threadIdx.x;
    int lane = tid & 63;
    int wv = tid >> 6;
    int r = tile >> 7;
    bool useFp = rUseFp[r] != 0;
    int widx = tile * WORDS_PER_TILE + (tid >> 3);
    int shift = (tid & 7) * 8;
    unsigned bT = (unsigned)(mT[widx] >> shift) & 0xFF;
    ull chw = useFp ? mFp[widx] : mNeg[widx];
    unsigned bCh = (unsigned)(chw >> shift) & 0xFF;
    const float4* x4 = (const float4*)x;
    int b4 = tile * (TILE / 4) + tid * 2;
    float4 a = x4[b4], b = x4[b4 + 1];
    float xv[8] = {a.x, a.y, a.z, a.w, b.x, b.y, b.z, b.w};
    int p = __popc(bT), c = __popc(bCh);
    int v = p | (c << 16);  // both halves <= 2048, no cross-carry
    // in-wave inclusive scan (6 shfl rounds, no barriers)
    int incl = v;
#pragma unroll
    for (int off = 1; off < 64; off <<= 1) {
        int n = __shfl_up(incl, off, 64);
        if (lane >= off) incl += n;
    }
    __shared__ int wtot[4];
    __shared__ __align__(16) float bufP[TILE];
    __shared__ __align__(16) float bufC[TILE];
    if (lane == 63) wtot[wv] = incl;
    __syncthreads();
    int base = 0;
    if (wv > 0) base += wtot[0];
    if (wv > 1) base += wtot[1];
    if (wv > 2) base += wtot[2];
    int tot = wtot[0] + wtot[1] + wtot[2] + wtot[3];
    int excl = base + incl - v;
    int ep = excl & 0xFFFF;
    int ec = (excl >> 16) & 0xFFFF;
#pragma unroll
    for (int e = 0; e < 8; ++e) {
        if ((bT >> e) & 1) bufP[ep++] = xv[e];
        if ((bCh >> e) & 1) bufC[ec++] = xv[e];
    }
    __syncthreads();
    int P = tot & 0xFFFF, C = (tot >> 16) & 0xFFFF;
    int rL = r << LOG2L;
    int pbase = rL + oPos[tile];
    // head: bring dest to 16B alignment
    int mis = (4 - (pbase & 3)) & 3;
    int h = mis < P ? mis : P;
    if (tid < h) xp[pbase + tid] = bufP[tid];
    int rem = P - h;
    int nv = rem >> 2;       // aligned float4 stores
    for (int j = tid; j < nv; j += TPB) {
        int o = h + 4 * j;
        float4 vv;
        vv.x = bufP[o]; vv.y = bufP[o + 1]; vv.z = bufP[o + 2]; vv.w = bufP[o + 3];
        *(float4*)&xp[pbase + o] = vv;   // global_store_dwordx4, 16B-aligned dest
    }
    int done = h + 4 * nv;
    if (tid < P - done) xp[pbase + done + tid] = bufP[done + tid];
    int cbase = rL + oCh[tile];
    for (int i = tid; i < C; i += TPB) xf[cbase + i] = bufC[i];   // cold (C==0 on this data)
}

// ------ K4: loss (R13 version: TPB=512, LBLK=32, dwordx4 gather, softplus identity). ------
// R14: K5 merged in via the last-block-done pattern: each block stores its partial,
// __threadfence (release), atomicAdd on a counter; the last block re-fences (acquire)
// and reduces all partials to out. Saves one launch + gap.
__global__ __launch_bounds__(TPB4)
void loss_kernel(const float* __restrict__ x, const ull* __restrict__ mT,
                 const float* __restrict__ xp, const float* __restrict__ xf,
                 const int* __restrict__ rCp, const int* __restrict__ rCc,
                 const ull* __restrict__ rMp, const ull* __restrict__ rMc,
                 double* __restrict__ partial, unsigned int* __restrict__ doneCnt,
                 float* __restrict__ out, double inv_ntot) {
    int r = blockIdx.x >> LOG2LBLK;            // 32 blocks per row
    int cb = (blockIdx.x & (LBLK - 1)) * CHUNK;
    int rL = r << LOG2L;
    int cp = rCp[r], cc = rCc[r];              // block-uniform scalars
    ull Mp = rMp[r], Mc = rMc[r];
    const float4* x4 = (const float4*)(x + rL + cb);
    const float* xpr = xp + rL;
    const float* xfr = xf + rL;
    const ull* mtr = mT + (rL >> 6);
    float local = 0.0f;
#pragma unroll
    for (int it = 0; it < LIT; ++it) {
        int o4 = it * TPB4 + threadIdx.x;
        unsigned l = (unsigned)(cb + (o4 << 2));
        float4 xv = x4[o4];
        unsigned tb = (unsigned)(mtr[l >> 6] >> (l & 63)) & 0xFu;
        float dps[4], dfs[4];
        if (cp > 0) {
            unsigned d = (unsigned)cp;
            unsigned q = (unsigned)(((ull)l * Mp) >> 40);
            unsigned m0 = l - q * d;
            if ((int)m0 <= (int)d - 4) {
                float4 v;
                __builtin_memcpy(&v, xpr + m0, 16);   // unaligned dwordx4, contiguous window
                dps[0] = v.x; dps[1] = v.y; dps[2] = v.z; dps[3] = v.w;
            } else {
                unsigned m1 = m0 + 1; if (m1 == d) m1 = 0;
                unsigned m2 = m1 + 1; if (m2 == d) m2 = 0;
                unsigned m3 = m2 + 1; if (m3 == d) m3 = 0;
                dps[0] = xpr[m0]; dps[1] = xpr[m1]; dps[2] = xpr[m2]; dps[3] = xpr[m3];
            }
        } else {
            dps[0] = dps[1] = dps[2] = dps[3] = 5.0f;
        }
        if (cc > 0) {
            unsigned d = (unsigned)cc;
            unsigned q = (unsigned)(((ull)l * Mc) >> 40);
            unsigned m0 = l - q * d;
            if ((int)m0 <= (int)d - 4) {
                float4 v;
                __builtin_memcpy(&v, xfr + m0, 16);
                dfs[0] = v.x; dfs[1] = v.y; dfs[2] = v.z; dfs[3] = v.w;
            } else {
                unsigned m1 = m0 + 1; if (m1 == d) m1 = 0;
                unsigned m2 = m1 + 1; if (m2 == d) m2 = 0;
                unsigned m3 = m2 + 1; if (m3 == d) m3 = 0;
                dfs[0] = xfr[m0]; dfs[1] = xfr[m1]; dfs[2] = xfr[m2]; dfs[3] = xfr[m3];
            }
        } else {
            dfs[0] = dfs[1] = dfs[2] = dfs[3] = -5.0f;
        }
        float xs[4] = {xv.x, xv.y, xv.z, xv.w};
#pragma unroll
        for (int k = 0; k < 4; ++k) {
            float sim = dps[k] * xs[k];
            float s1 = ((tb >> k) & 1) ? -sim : sim;   // softplus(s)-s == softplus(-s)
            local += softplus_f(s1) + softplus_f(-dps[k]) + 0.1f * softplus_f(dps[k] * dfs[k]);
        }
    }
    __shared__ double sd[TPB4];
    __shared__ bool sLast;
    int tid = threadIdx.x;
    sd[tid] = (double)local;
    __syncthreads();
    for (int off = TPB4 / 2; off > 0; off >>= 1) {
        if (tid < off) sd[tid] += sd[tid + off];
        __syncthreads();
    }
    if (tid == 0) {
        partial[blockIdx.x] = sd[0];
        __threadfence();                       // release: publish partial
        unsigned old = atomicAdd(doneCnt, 1u); // device-scope
        sLast = (old == (unsigned)(gridDim.x - 1));
    }
    __syncthreads();
    if (sLast) {
        __threadfence();                       // acquire: see all partials
        double s = 0.0;
        int n = (int)gridDim.x;
        for (int i = tid; i < n; i += TPB4) s += partial[i];
        sd[tid] = s;
        __syncthreads();
        for (int off = TPB4 / 2; off > 0; off >>= 1) {
            if (tid < off) sd[tid] += sd[tid + off];
            __syncthreads();
        }
        if (tid == 0) out[0] = (float)(sd[0] * inv_ntot);  // overwrites poison
    }
}

extern "C" void kernel_launch(void* const* d_in, const int* in_sizes, int n_in,
                              void* d_out, int out_size, void* d_ws, size_t ws_size,
                              hipStream_t stream) {
    const float* x = (const float*)d_in[0];
    const float* t = (const float*)d_in[1];
    float* out = (float*)d_out;

    int ntot = in_sizes[0];          // 12,582,912
    int R = ntot >> LOG2L;           // 48
    int numTiles = ntot / TILE;      // 6144
    int nwords = ntot / 64;          // 196,608
    int nMaskBlk = ntot / (SPB * W); // 1536
    int nLossBlk = R * LBLK;         // 1536

    char* ws = (char*)d_ws;
    size_t off = 0;
    auto alloc = [&](size_t bytes) {
        size_t p = off;
        off = (off + bytes + 255) & ~(size_t)255;
        return (void*)(ws + p);
    };
    ull* mT   = (ull*)alloc((size_t)nwords * 8);
    ull* mFp  = (ull*)alloc((size_t)nwords * 8);
    ull* mNeg = (ull*)alloc((size_t)nwords * 8);
    int* cPos = (int*)alloc(numTiles * sizeof(int));
    int* cFp  = (int*)alloc(numTiles * sizeof(int));
    int* cNeg = (int*)alloc(numTiles * sizeof(int));
    int* oPos = (int*)alloc(numTiles * sizeof(int));
    int* oCh  = (int*)alloc(numTiles * sizeof(int));
    int* rCp = (int*)alloc(R * sizeof(int));
    int* rCc = (int*)alloc(R * sizeof(int));
    int* rUseFp = (int*)alloc(R * sizeof(int));
    ull* rMp = (ull*)alloc(R * sizeof(ull));
    ull* rMc = (ull*)alloc(R * sizeof(ull));
    double* partial = (double*)alloc((size_t)nLossBlk * sizeof(double));
    unsigned int* doneCnt = (unsigned int*)alloc(sizeof(unsigned int));
    float* xp = (float*)alloc((size_t)ntot * sizeof(float));
    float* xf = (float*)alloc((size_t)ntot * sizeof(float));

    fused_mask_kernel<<<nMaskBlk, TPB1, 0, stream>>>(x, t, mT, mFp, mNeg,
                                                     cPos, cFp, cNeg, doneCnt);
    scan_kernel<<<R, TILES_PER_ROW, 0, stream>>>(cPos, cFp, cNeg, oPos, oCh,
                                                 rCp, rCc, rMp, rMc, rUseFp);
    scatter_kernel<<<numTiles, TPB, 0, stream>>>(x, mT, mFp, mNeg, oPos, oCh, rUseFp, xp, xf);
    loss_kernel<<<nLossBlk, TPB4, 0, stream>>>(x, mT, xp, xf, rCp, rCc, rMp, rMc,
                                               partial, doneCnt, out, 1.0 / (double)ntot);
}

// Round 15
// 158.183 us; speedup vs baseline: 1.2027x; 1.2027x over previous
//
#include <hip/hip_runtime.h>
#include <math.h>

// Problem constants (B=16, C=3, H=W=512) -> 48 "rows" (images) of L = 262144 elements.
constexpr int W = 512;
constexpr int HIMG = 512;
constexpr int L = 1 << 18;                // elements per row
constexpr int LOG2L = 18;
constexpr int TPB = 256;
constexpr int TPB1 = 512;                 // K1 block size (R10-proven; 1024 unattributable in R14, reverted)
constexpr int TPB4 = 512;                 // K4 block size (R13-proven)
constexpr int TILE = 2048;                // elements per scatter tile (= 4 scanlines)
constexpr int TILES_PER_ROW = L / TILE;   // 128
constexpr int WORDS_PER_TILE = TILE / 64; // 32
constexpr int SPB = 16;                   // scanlines per fused-mask block (R8-proven)
constexpr int HALO = 3;
constexpr int HBUF = SPB + 2 * HALO;      // 22
constexpr int BLK_PER_IMG = HIMG / SPB;   // 32
constexpr int LBLK = 32;                  // loss blocks per row (1536 blocks = fully-resident cohort)
constexpr int LOG2LBLK = 5;
constexpr int CHUNK = L / LBLK;           // 8192 elements per loss block
constexpr int LIT = CHUNK / (TPB4 * 4);   // 4 float4 iterations per thread

typedef unsigned long long ull;

// softplus via native v_exp_f32 / v_log_f32 (abs err ~1e-6; threshold 3.6e-2)
__device__ __forceinline__ float softplus_f(float v) {
    return fmaxf(v, 0.0f) +
           0.6931471805599453f *
               __builtin_amdgcn_logf(1.0f + __builtin_amdgcn_exp2f(-fabsf(v) * 1.4426950408889634f));
}

__device__ __forceinline__ ull hdil7(ull prev, ull cur, ull next) {
    ull r = cur;
    r |= (cur >> 1) | (next << 63);
    r |= (cur >> 2) | (next << 62);
    r |= (cur >> 3) | (next << 61);
    r |= (cur << 1) | (prev >> 63);
    r |= (cur << 2) | (prev >> 62);
    r |= (cur << 3) | (prev >> 61);
    return r;
}

template <typename T>
__device__ __forceinline__ T sel8(const T* a, int k) {
    return k == 0 ? a[0] : k == 1 ? a[1] : k == 2 ? a[2] : k == 3 ? a[3]
         : k == 4 ? a[4] : k == 5 ? a[5] : k == 6 ? a[6] : a[7];
}

// ------ K1: fused masks + 7x7 dilation + per-tile counts. One block = 16 scanlines. ------
// TPB=512 at grid 1536 (R10-proven: 100% occupancy cap, unchanged instruction count).
// R14's fence-merge is reverted, so no doneCnt here.
__global__ __launch_bounds__(TPB1)
void fused_mask_kernel(const float* __restrict__ x, const float* __restrict__ t,
                       ull* __restrict__ mT, ull* __restrict__ mFp, ull* __restrict__ mNeg,
                       int* __restrict__ cPos, int* __restrict__ cFp, int* __restrict__ cNeg) {
    int b = blockIdx.x;
    int img = b >> 5;              // BLK_PER_IMG = 32
    int y0 = (b & 31) * SPB;       // image-local scanline base
    int gs0 = img * HIMG + y0;     // global scanline index of own base

    __shared__ ull hbuf[HBUF][8];  // h-dilated words incl. halo
    __shared__ ull tbuf[SPB][8];
    __shared__ ull xbuf[SPB][8];

    int lane = threadIdx.x & 63;
    int wv = threadIdx.x >> 6;     // wave 0..7
    int ylo = (y0 - HALO < 0) ? 0 : y0 - HALO;
    int yhi = (y0 + SPB - 1 + HALO > HIMG - 1) ? HIMG - 1 : y0 + SPB - 1 + HALO;

    for (int yl = ylo + wv; yl <= yhi; yl += 8) {
        int gbase = (img * HIMG + yl) * W;
        bool own = (yl >= y0) && (yl < y0 + SPB);
        ull wt[8], wx[8], h[8];
#pragma unroll
        for (int k = 0; k < 8; ++k) wt[k] = __ballot(t[gbase + k * 64 + lane] > 0.0f);
        if (own) {
#pragma unroll
            for (int k = 0; k < 8; ++k) wx[k] = __ballot(x[gbase + k * 64 + lane] > 0.0f);
        }
#pragma unroll
        for (int k = 0; k < 8; ++k) {
            ull cur = wt[k];
            ull prev = k ? wt[k - 1]
                         : ((((cur >> 1) & 1ull) << 63) | (((cur >> 2) & 1ull) << 62) |
                            (((cur >> 3) & 1ull) << 61));
            ull next = (k < 7) ? wt[k + 1]
                               : (((cur >> 62) & 1ull) | (((cur >> 61) & 1ull) << 1) |
                                  (((cur >> 60) & 1ull) << 2));
            h[k] = hdil7(prev, cur, next);
        }
        int hy = yl - (y0 - HALO);
        int k = lane & 7;
        if (lane < 8) {
            hbuf[hy][k] = sel8(h, k);
        } else if (own && lane < 16) {
            tbuf[yl - y0][k] = sel8(wt, k);
            mT[(img * HIMG + yl) * 8 + k] = sel8(wt, k);
        } else if (own && lane < 24) {
            xbuf[yl - y0][k] = sel8(wx, k);
        }
    }
    __syncthreads();

    // phase 2: vertical dilation + per-word popcounts; thread = one own word
    int tid = threadIdx.x;
    if (tid < SPB * 8) {           // 128 active threads (16 scanlines x 8 words)
        int ys = tid >> 3;         // own scanline offset 0..15
        int c = tid & 7;
        int y = y0 + ys;
        ull wa = 0;
#pragma unroll
        for (int d = -3; d <= 3; ++d) {
            int yy = y + d;
            yy = yy < 0 ? -yy : (yy > HIMG - 1 ? 2 * (HIMG - 1) - yy : yy);
            wa |= hbuf[yy - (y0 - HALO)][c];
        }
        ull tw = tbuf[ys][c];
        ull fp = xbuf[ys][c] & ~wa;
        ull ng = ~wa;
        int gw = gs0 * 8 + tid;
        mFp[gw] = fp;
        mNeg[gw] = ng;
        int pT = __popcll(tw), pF = __popcll(fp), pN = __popcll(ng);
        // reduce within 32-thread groups (one tile = 4 scanlines = 32 words)
#pragma unroll
        for (int m = 1; m < 32; m <<= 1) {
            pT += __shfl_xor(pT, m, 64);
            pF += __shfl_xor(pF, m, 64);
            pN += __shfl_xor(pN, m, 64);
        }
        if ((lane & 31) == 0) {
            int tile = img * TILES_PER_ROW + (y0 >> 2) + (tid >> 5);
            cPos[tile] = pT; cFp[tile] = pF; cNeg[tile] = pN;
        }
    }
}

// ------ K2: per-row scan of tile counts + magic divisors (R10 version) ------
__global__ void scan_kernel(const int* __restrict__ cPos, const int* __restrict__ cFp,
                            const int* __restrict__ cNeg,
                            int* __restrict__ oPos, int* __restrict__ oCh,
                            int* __restrict__ rCp, int* __restrict__ rCc,
                            ull* __restrict__ rMp, ull* __restrict__ rMc,
                            int* __restrict__ rUseFp) {
    int r = blockIdx.x;
    int tid = threadIdx.x;  // blockDim == TILES_PER_ROW
    __shared__ int ssp[TILES_PER_ROW], ssf[TILES_PER_ROW], ssn[TILES_PER_ROW];
    int myp = cPos[r * TILES_PER_ROW + tid];
    int myf = cFp[r * TILES_PER_ROW + tid];
    int myn = cNeg[r * TILES_PER_ROW + tid];
    ssp[tid] = myp; ssf[tid] = myf; ssn[tid] = myn;
    __syncthreads();
    for (int off = 1; off < TILES_PER_ROW; off <<= 1) {
        int ap = 0, af = 0, an = 0;
        if (tid >= off) { ap = ssp[tid - off]; af = ssf[tid - off]; an = ssn[tid - off]; }
        __syncthreads();
        if (tid >= off) { ssp[tid] += ap; ssf[tid] += af; ssn[tid] += an; }
        __syncthreads();
    }
    int cp = ssp[TILES_PER_ROW - 1], cf = ssf[TILES_PER_ROW - 1], cn = ssn[TILES_PER_ROW - 1];
    bool useFp = cf > 0;
    int tile = r * TILES_PER_ROW + tid;
    oPos[tile] = ssp[tid] - myp;
    oCh[tile] = useFp ? (ssf[tid] - myf) : (ssn[tid] - myn);
    if (tid == 0) {
        int cc = useFp ? cf : cn;
        rCp[r] = cp; rCc[r] = cc; rUseFp[r] = useFp ? 1 : 0;
        ull dp_ = (ull)(cp > 0 ? cp : 1);
        ull dc_ = (ull)(cc > 0 ? cc : 1);
        rMp[r] = ((1ull << 40) + dp_ - 1) / dp_;  // exact floor(n/d) for n < 2^22
        rMc[r] = ((1ull << 40) + dc_ - 1) / dc_;
    }
}

// ------ K3: scatter-compaction (R12 version: shfl-scan + aligned-vectorized stores) ------
__global__ __launch_bounds__(TPB)
void scatter_kernel(const float* __restrict__ x, const ull* __restrict__ mT,
                    const ull* __restrict__ mFp, const ull* __restrict__ mNeg,
                    const int* __restrict__ oPos, const int* __restrict__ oCh,
                    const int* __restrict__ rUseFp,
                    float* __restrict__ xp, float* __restrict__ xf) {
    int tile = blockIdx.x;
    int tid = threadIdx.x;
    int lane = tid & 63;
    int wv = tid >> 6;
    int r = tile >> 7;
    bool useFp = rUseFp[r] != 0;
    int widx = tile * WORDS_PER_TILE + (tid >> 3);
    int shift = (tid & 7) * 8;
    unsigned bT = (unsigned)(mT[widx] >> shift) & 0xFF;
    ull chw = useFp ? mFp[widx] : mNeg[widx];
    unsigned bCh = (unsigned)(chw >> shift) & 0xFF;
    const float4* x4 = (const float4*)x;
    int b4 = tile * (TILE / 4) + tid * 2;
    float4 a = x4[b4], b = x4[b4 + 1];
    float xv[8] = {a.x, a.y, a.z, a.w, b.x, b.y, b.z, b.w};
    int p = __popc(bT), c = __popc(bCh);
    int v = p | (c << 16);  // both halves <= 2048, no cross-carry
    // in-wave inclusive scan (6 shfl rounds, no barriers)
    int incl = v;
#pragma unroll
    for (int off = 1; off < 64; off <<= 1) {
        int n = __shfl_up(incl, off, 64);
        if (lane >= off) incl += n;
    }
    __shared__ int wtot[4];
    __shared__ __align__(16) float bufP[TILE];
    __shared__ __align__(16) float bufC[TILE];
    if (lane == 63) wtot[wv] = incl;
    __syncthreads();
    int base = 0;
    if (wv > 0) base += wtot[0];
    if (wv > 1) base += wtot[1];
    if (wv > 2) base += wtot[2];
    int tot = wtot[0] + wtot[1] + wtot[2] + wtot[3];
    int excl = base + incl - v;
    int ep = excl & 0xFFFF;
    int ec = (excl >> 16) & 0xFFFF;
#pragma unroll
    for (int e = 0; e < 8; ++e) {
        if ((bT >> e) & 1) bufP[ep++] = xv[e];
        if ((bCh >> e) & 1) bufC[ec++] = xv[e];
    }
    __syncthreads();
    int P = tot & 0xFFFF, C = (tot >> 16) & 0xFFFF;
    int rL = r << LOG2L;
    int pbase = rL + oPos[tile];
    // head: bring dest to 16B alignment
    int mis = (4 - (pbase & 3)) & 3;
    int h = mis < P ? mis : P;
    if (tid < h) xp[pbase + tid] = bufP[tid];
    int rem = P - h;
    int nv = rem >> 2;       // aligned float4 stores
    for (int j = tid; j < nv; j += TPB) {
        int o = h + 4 * j;
        float4 vv;
        vv.x = bufP[o]; vv.y = bufP[o + 1]; vv.z = bufP[o + 2]; vv.w = bufP[o + 3];
        *(float4*)&xp[pbase + o] = vv;   // global_store_dwordx4, 16B-aligned dest
    }
    int done = h + 4 * nv;
    if (tid < P - done) xp[pbase + done + tid] = bufP[done + tid];
    int cbase = rL + oCh[tile];
    for (int i = tid; i < C; i += TPB) xf[cbase + i] = bufC[i];   // cold (C==0 on this data)
}

// ------ K4: loss (R13 version: TPB=512, LBLK=32, dwordx4 gather, softplus identity). ------
// R14's fence-merge reverted: per-block __threadfence + device atomic cost ~+20us on
// loss (53us, even on cached replays). Partials + separate 1-block reduce restored.
__global__ __launch_bounds__(TPB4)
void loss_kernel(const float* __restrict__ x, const ull* __restrict__ mT,
                 const float* __restrict__ xp, const float* __restrict__ xf,
                 const int* __restrict__ rCp, const int* __restrict__ rCc,
                 const ull* __restrict__ rMp, const ull* __restrict__ rMc,
                 double* __restrict__ partial) {
    int r = blockIdx.x >> LOG2LBLK;            // 32 blocks per row
    int cb = (blockIdx.x & (LBLK - 1)) * CHUNK;
    int rL = r << LOG2L;
    int cp = rCp[r], cc = rCc[r];              // block-uniform scalars
    ull Mp = rMp[r], Mc = rMc[r];
    const float4* x4 = (const float4*)(x + rL + cb);
    const float* xpr = xp + rL;
    const float* xfr = xf + rL;
    const ull* mtr = mT + (rL >> 6);
    float local = 0.0f;
#pragma unroll
    for (int it = 0; it < LIT; ++it) {
        int o4 = it * TPB4 + threadIdx.x;
        unsigned l = (unsigned)(cb + (o4 << 2));
        float4 xv = x4[o4];
        unsigned tb = (unsigned)(mtr[l >> 6] >> (l & 63)) & 0xFu;
        float dps[4], dfs[4];
        if (cp > 0) {
            unsigned d = (unsigned)cp;
            unsigned q = (unsigned)(((ull)l * Mp) >> 40);
            unsigned m0 = l - q * d;
            if ((int)m0 <= (int)d - 4) {
                float4 v;
                __builtin_memcpy(&v, xpr + m0, 16);   // unaligned dwordx4, contiguous window
                dps[0] = v.x; dps[1] = v.y; dps[2] = v.z; dps[3] = v.w;
            } else {
                unsigned m1 = m0 + 1; if (m1 == d) m1 = 0;
                unsigned m2 = m1 + 1; if (m2 == d) m2 = 0;
                unsigned m3 = m2 + 1; if (m3 == d) m3 = 0;
                dps[0] = xpr[m0]; dps[1] = xpr[m1]; dps[2] = xpr[m2]; dps[3] = xpr[m3];
            }
        } else {
            dps[0] = dps[1] = dps[2] = dps[3] = 5.0f;
        }
        if (cc > 0) {
            unsigned d = (unsigned)cc;
            unsigned q = (unsigned)(((ull)l * Mc) >> 40);
            unsigned m0 = l - q * d;
            if ((int)m0 <= (int)d - 4) {
                float4 v;
                __builtin_memcpy(&v, xfr + m0, 16);
                dfs[0] = v.x; dfs[1] = v.y; dfs[2] = v.z; dfs[3] = v.w;
            } else {
                unsigned m1 = m0 + 1; if (m1 == d) m1 = 0;
                unsigned m2 = m1 + 1; if (m2 == d) m2 = 0;
                unsigned m3 = m2 + 1; if (m3 == d) m3 = 0;
                dfs[0] = xfr[m0]; dfs[1] = xfr[m1]; dfs[2] = xfr[m2]; dfs[3] = xfr[m3];
            }
        } else {
            dfs[0] = dfs[1] = dfs[2] = dfs[3] = -5.0f;
        }
        float xs[4] = {xv.x, xv.y, xv.z, xv.w};
#pragma unroll
        for (int k = 0; k < 4; ++k) {
            float sim = dps[k] * xs[k];
            float s1 = ((tb >> k) & 1) ? -sim : sim;   // softplus(s)-s == softplus(-s)
            local += softplus_f(s1) + softplus_f(-dps[k]) + 0.1f * softplus_f(dps[k] * dfs[k]);
        }
    }
    __shared__ double sd[TPB4];
    int tid = threadIdx.x;
    sd[tid] = (double)local;
    __syncthreads();
    for (int off = TPB4 / 2; off > 0; off >>= 1) {
        if (tid < off) sd[tid] += sd[tid + off];
        __syncthreads();
    }
    if (tid == 0) partial[blockIdx.x] = sd[0];
}

// ------ K5: final reduce of per-block partials (1 block) ------
__global__ __launch_bounds__(TPB)
void final_reduce(const double* __restrict__ partial, int n,
                  float* __restrict__ out, double inv_ntot) {
    __shared__ double sd[TPB];
    double s = 0.0;
    for (int i = threadIdx.x; i < n; i += TPB) s += partial[i];
    sd[threadIdx.x] = s;
    __syncthreads();
    for (int off = TPB / 2; off > 0; off >>= 1) {
        if (threadIdx.x < off) sd[threadIdx.x] += sd[threadIdx.x + off];
        __syncthreads();
    }
    if (threadIdx.x == 0) out[0] = (float)(sd[0] * inv_ntot);  // overwrites poison
}

extern "C" void kernel_launch(void* const* d_in, const int* in_sizes, int n_in,
                              void* d_out, int out_size, void* d_ws, size_t ws_size,
                              hipStream_t stream) {
    const float* x = (const float*)d_in[0];
    const float* t = (const float*)d_in[1];
    float* out = (float*)d_out;

    int ntot = in_sizes[0];          // 12,582,912
    int R = ntot >> LOG2L;           // 48
    int numTiles = ntot / TILE;      // 6144
    int nwords = ntot / 64;          // 196,608
    int nMaskBlk = ntot / (SPB * W); // 1536
    int nLossBlk = R * LBLK;         // 1536

    char* ws = (char*)d_ws;
    size_t off = 0;
    auto alloc = [&](size_t bytes) {
        size_t p = off;
        off = (off + bytes + 255) & ~(size_t)255;
        return (void*)(ws + p);
    };
    ull* mT   = (ull*)alloc((size_t)nwords * 8);
    ull* mFp  = (ull*)alloc((size_t)nwords * 8);
    ull* mNeg = (ull*)alloc((size_t)nwords * 8);
    int* cPos = (int*)alloc(numTiles * sizeof(int));
    int* cFp  = (int*)alloc(numTiles * sizeof(int));
    int* cNeg = (int*)alloc(numTiles * sizeof(int));
    int* oPos = (int*)alloc(numTiles * sizeof(int));
    int* oCh  = (int*)alloc(numTiles * sizeof(int));
    int* rCp = (int*)alloc(R * sizeof(int));
    int* rCc = (int*)alloc(R * sizeof(int));
    int* rUseFp = (int*)alloc(R * sizeof(int));
    ull* rMp = (ull*)alloc(R * sizeof(ull));
    ull* rMc = (ull*)alloc(R * sizeof(ull));
    double* partial = (double*)alloc((size_t)nLossBlk * sizeof(double));
    float* xp = (float*)alloc((size_t)ntot * sizeof(float));
    float* xf = (float*)alloc((size_t)ntot * sizeof(float));

    fused_mask_kernel<<<nMaskBlk, TPB1, 0, stream>>>(x, t, mT, mFp, mNeg, cPos, cFp, cNeg);
    scan_kernel<<<R, TILES_PER_ROW, 0, stream>>>(cPos, cFp, cNeg, oPos, oCh,
                                                 rCp, rCc, rMp, rMc, rUseFp);
    scatter_kernel<<<numTiles, TPB, 0, stream>>>(x, mT, mFp, mNeg, oPos, oCh, rUseFp, xp, xf);
    loss_kernel<<<nLossBlk, TPB4, 0, stream>>>(x, mT, xp, xf, rCp, rCc, rMp, rMc, partial);
    final_reduce<<<1, TPB, 0, stream>>>(partial, nLossBlk, out, 1.0 / (double)ntot);
}